// Round 8
// baseline (492.606 us; speedup 1.0000x reference)
//
#include <hip/hip_runtime.h>
#include <math.h>

#define NN 50000
#define EE 800000
#define GG 256
#define NB_SCAN 196   // ceil(50000/256)

__device__ __forceinline__ float gelu_f(float v){
    return 0.5f * v * (1.0f + erff(v * 0.70710678118654752f));
}

// ---------------- degree count over dst ----------------
__global__ __launch_bounds__(256) void k_deg(const int* __restrict__ dst, int* __restrict__ deg, int e){
    int i = blockIdx.x * blockDim.x + threadIdx.x;
    if (i < e) atomicAdd(&deg[dst[i]], 1);
}

// ---------------- scan phase 1: per-block sums ----------------
__global__ __launch_bounds__(256) void k_bsum(const int* __restrict__ deg, int* __restrict__ bsum, int n){
    __shared__ int s[256];
    int t = threadIdx.x;
    int i = blockIdx.x * 256 + t;
    s[t] = (i < n) ? deg[i] : 0;
    __syncthreads();
    for (int off = 128; off > 0; off >>= 1){
        if (t < off) s[t] += s[t + off];
        __syncthreads();
    }
    if (t == 0) bsum[blockIdx.x] = s[0];
}

// ---------------- scan phase 2: single-block scan of partials ----------------
__global__ __launch_bounds__(256) void k_pscan(const int* __restrict__ bsum, int* __restrict__ boff,
                                               int* __restrict__ rp, int nb, int n){
    __shared__ int s[256];
    int t = threadIdx.x;
    int v = (t < nb) ? bsum[t] : 0;
    s[t] = v;
    __syncthreads();
    for (int off = 1; off < 256; off <<= 1){
        int u = (t >= off) ? s[t - off] : 0;
        __syncthreads();
        s[t] += u;
        __syncthreads();
    }
    if (t < nb) boff[t] = s[t] - v;          // exclusive block offset
    if (t == nb - 1) rp[n] = s[t];           // total (= E)
}

// ---------------- scan phase 3: apply + derived per-node arrays ----------------
__global__ __launch_bounds__(256) void k_apply(const int* __restrict__ deg, const int* __restrict__ boff,
                                               int* __restrict__ rp, int* __restrict__ cursor,
                                               float* __restrict__ dis, float* __restrict__ invdis,
                                               float* __restrict__ dsum, const float* __restrict__ x,
                                               float* __restrict__ xs, int n){
    __shared__ int s[256];
    int t = threadIdx.x;
    int i = blockIdx.x * 256 + t;
    int d = (i < n) ? deg[i] : 0;
    s[t] = d;
    __syncthreads();
    for (int off = 1; off < 256; off <<= 1){
        int u = (t >= off) ? s[t - off] : 0;
        __syncthreads();
        s[t] += u;
        __syncthreads();
    }
    if (i < n){
        int excl = s[t] - d + boff[blockIdx.x];
        rp[i] = excl;
        cursor[i] = excl;
        float dv = rsqrtf((float)(d + 1));   // +1 self loop
        dis[i] = dv;
        invdis[i] = sqrtf((float)(d + 1));
        dsum[i] = dv;                        // self term of dsum; edges added in k_fill
        xs[i] = dv * x[i];                   // pre-scaled input feature
    }
}

// ---------------- CSR fill (col only) + dsum accumulation ----------------
__global__ __launch_bounds__(256) void k_fill(const int* __restrict__ src, const int* __restrict__ dst,
                                              const float* __restrict__ dis, int* __restrict__ cursor,
                                              float* __restrict__ dsum, int* __restrict__ col, int e){
    int i = blockIdx.x * blockDim.x + threadIdx.x;
    if (i < e){
        int d = dst[i], s = src[i];
        int p = atomicAdd(&cursor[d], 1);
        col[p] = s;
        atomicAdd(&dsum[d], dis[s]);
    }
}

// ---------------- layer-1 aggregation of xs (C=1): edge-parallel atomics ----------------
__global__ __launch_bounds__(256) void k_agg1(const float* __restrict__ xs, const int* __restrict__ src,
                                              const int* __restrict__ dst, float* __restrict__ agg, int e){
    int i = blockIdx.x * blockDim.x + threadIdx.x;
    if (i < e) atomicAdd(&agg[dst[i]], xs[src[i]]);
}

// ---------------- gather of pre-scaled hs with inline BN affine (float4, 4-edge unroll) ----------------
// out[d] = dis_d * ( sc * (sum_{s in N(d)} hs[s] + hs[d]) + sh * dsum[d] )
template<int C>
__global__ __launch_bounds__(256) void k_gather(const float* __restrict__ hs, const int* __restrict__ rp,
                                                const int* __restrict__ col, const float* __restrict__ dis,
                                                const float* __restrict__ dsum, const float* __restrict__ stat,
                                                const float* __restrict__ gamma, const float* __restrict__ beta,
                                                float* __restrict__ outp, int n){
    constexpr int TPN = C / 4;
    int i = blockIdx.x * 256 + threadIdx.x;
    int node = i / TPN, q = i % TPN;
    if (node >= n) return;
    int c0 = q * 4;
    const float invn = 1.0f / (float)NN;
    float scv[4], shv[4];
#pragma unroll
    for (int u = 0; u < 4; u++){
        float mean = stat[c0 + u] * invn;
        float var  = stat[128 + c0 + u] * invn - mean * mean;
        float sc   = gamma[c0 + u] * rsqrtf(var + 1e-5f);
        scv[u] = sc;
        shv[u] = beta[c0 + u] - mean * sc;
    }
    const float4* h4 = (const float4*)hs;
    int beg = rp[node], end = rp[node + 1];
    float a0 = 0.f, a1 = 0.f, a2 = 0.f, a3 = 0.f;
    float b0 = 0.f, b1 = 0.f, b2 = 0.f, b3 = 0.f;
    int j = beg;
    for (; j + 3 < end; j += 4){
        int i0 = col[j], i1 = col[j+1], i2 = col[j+2], i3 = col[j+3];
        float4 v0 = h4[i0 * TPN + q];
        float4 v1 = h4[i1 * TPN + q];
        float4 v2 = h4[i2 * TPN + q];
        float4 v3 = h4[i3 * TPN + q];
        a0 += v0.x; a1 += v0.y; a2 += v0.z; a3 += v0.w;
        b0 += v1.x; b1 += v1.y; b2 += v1.z; b3 += v1.w;
        a0 += v2.x; a1 += v2.y; a2 += v2.z; a3 += v2.w;
        b0 += v3.x; b1 += v3.y; b2 += v3.z; b3 += v3.w;
    }
    for (; j < end; j++){
        float4 v = h4[col[j] * TPN + q];
        a0 += v.x; a1 += v.y; a2 += v.z; a3 += v.w;
    }
    float4 vs = h4[node * TPN + q];    // self loop (weight 1 in pre-scaled space)
    a0 += vs.x; a1 += vs.y; a2 += vs.z; a3 += vs.w;
    a0 += b0; a1 += b1; a2 += b2; a3 += b3;
    float dn = dis[node];
    float dsm = dsum[node];
    float4 r = make_float4((a0 * scv[0] + shv[0] * dsm) * dn,
                           (a1 * scv[1] + shv[1] * dsm) * dn,
                           (a2 * scv[2] + shv[2] * dsm) * dn,
                           (a3 * scv[3] + shv[3] * dsm) * dn);
    ((float4*)outp)[node * TPN + q] = r;
}

// ---------------- layer 1: 1->16 linear + bias + GELU, output pre-scaled by dis ----------------
__global__ __launch_bounds__(256) void k_lin1(const float* __restrict__ agg1, const float* __restrict__ xs,
                                              const float* __restrict__ dis, const float* __restrict__ W,
                                              const float* __restrict__ bias, float* __restrict__ outp, int n){
    int i = blockIdx.x * 256 + threadIdx.x;
    int node = i / 16, c = i % 16;
    if (node >= n) return;
    float dn = dis[node];
    float a = dn * (agg1[node] + xs[node]);   // self term added here (no atomic needed)
    outp[i] = gelu_f(bias[c] + a * W[c]) * dn;
}

// ---------------- dense linear + bias + GELU: 2 nodes x 4 channels per thread ----------------
// SCALE: multiply output by dis[node] (pre-scale for the next gather). Layer 4: SCALE=false.
template<int CIN, int COUT, bool SCALE>
__global__ __launch_bounds__(256) void k_linT(const float* __restrict__ xin, const float* __restrict__ dis,
                                              const float* __restrict__ W,
                                              const float* __restrict__ bias, float* __restrict__ outp, int n){
    constexpr int QC = COUT / 4;      // float4 channel groups
    constexpr int K4 = CIN / 4;       // float4 K groups
    int i = blockIdx.x * 256 + threadIdx.x;
    int pair = i / QC, q = i % QC;
    int n0 = pair * 2;                 // NN % 2 == 0
    if (n0 >= n) return;
    const float4* xa = (const float4*)(xin + (size_t)n0 * CIN);
    const float4* xb = (const float4*)(xin + (size_t)(n0 + 1) * CIN);
    const float4* Wq = (const float4*)W + q;      // row k at Wq[k * QC]
    float4 bb = ((const float4*)bias)[q];
    float aA0 = bb.x, aA1 = bb.y, aA2 = bb.z, aA3 = bb.w;
    float aB0 = bb.x, aB1 = bb.y, aB2 = bb.z, aB3 = bb.w;
#pragma unroll 1
    for (int k4 = 0; k4 < K4; k4++){
        float4 xA = xa[k4];
        float4 xB = xb[k4];
        float4 w0 = Wq[(k4 * 4 + 0) * QC];
        float4 w1 = Wq[(k4 * 4 + 1) * QC];
        float4 w2 = Wq[(k4 * 4 + 2) * QC];
        float4 w3 = Wq[(k4 * 4 + 3) * QC];
        aA0 += xA.x*w0.x + xA.y*w1.x + xA.z*w2.x + xA.w*w3.x;
        aA1 += xA.x*w0.y + xA.y*w1.y + xA.z*w2.y + xA.w*w3.y;
        aA2 += xA.x*w0.z + xA.y*w1.z + xA.z*w2.z + xA.w*w3.z;
        aA3 += xA.x*w0.w + xA.y*w1.w + xA.z*w2.w + xA.w*w3.w;
        aB0 += xB.x*w0.x + xB.y*w1.x + xB.z*w2.x + xB.w*w3.x;
        aB1 += xB.x*w0.y + xB.y*w1.y + xB.z*w2.y + xB.w*w3.y;
        aB2 += xB.x*w0.z + xB.y*w1.z + xB.z*w2.z + xB.w*w3.z;
        aB3 += xB.x*w0.w + xB.y*w1.w + xB.z*w2.w + xB.w*w3.w;
    }
    float sA = SCALE ? dis[n0] : 1.0f;
    float sB = SCALE ? dis[n0 + 1] : 1.0f;
    float4* o4 = (float4*)outp;
    o4[(size_t)n0 * QC + q]       = make_float4(gelu_f(aA0)*sA, gelu_f(aA1)*sA, gelu_f(aA2)*sA, gelu_f(aA3)*sA);
    o4[(size_t)(n0 + 1) * QC + q] = make_float4(gelu_f(aB0)*sB, gelu_f(aB1)*sB, gelu_f(aB2)*sB, gelu_f(aB3)*sB);
}

// ---------------- BN stats over raw h (de-scale pre-scaled hs by invdis) ----------------
template<int C>
__global__ __launch_bounds__(256) void k_stats(const float* __restrict__ hs, const float* __restrict__ invdis,
                                               float* __restrict__ stat, int n){
    constexpr int REP = 256 / C;
    int t = threadIdx.x;
    int rep = t / C;
    int c = t % C;
    float s = 0.f, q = 0.f;
    for (int row = blockIdx.x * REP + rep; row < n; row += gridDim.x * REP){
        float v = hs[(long long)row * C + c] * invdis[row];
        s += v; q += v * v;
    }
    __shared__ float ss[256], sq[256];
    ss[t] = s; sq[t] = q;
    __syncthreads();
    for (int off = 128; off >= C; off >>= 1){
        if (t < off){ ss[t] += ss[t + off]; sq[t] += sq[t + off]; }
        __syncthreads();
    }
    if (t < C){
        atomicAdd(&stat[t], ss[t]);
        atomicAdd(&stat[128 + t], sq[t]);
    }
}

// ---------------- mean-pool: one block per graph, binary search sorted batch, no atomics ----------------
__global__ __launch_bounds__(128) void k_pool(const float* __restrict__ h4, const int* __restrict__ batch,
                                              float* __restrict__ pool, int n){
    int g = blockIdx.x;
    int t = threadIdx.x;
    int lo = 0, hi = n;
    while (lo < hi){ int mid = (lo + hi) >> 1; if (batch[mid] < g) lo = mid + 1; else hi = mid; }
    int s = lo;
    hi = n;
    while (lo < hi){ int mid = (lo + hi) >> 1; if (batch[mid] < g + 1) lo = mid + 1; else hi = mid; }
    int e = lo;
    float a0 = 0.f, a1 = 0.f, a2 = 0.f, a3 = 0.f;
    int node = s;
    for (; node + 3 < e; node += 4){
        a0 += h4[(size_t)(node + 0) * 128 + t];
        a1 += h4[(size_t)(node + 1) * 128 + t];
        a2 += h4[(size_t)(node + 2) * 128 + t];
        a3 += h4[(size_t)(node + 3) * 128 + t];
    }
    for (; node < e; node++) a0 += h4[(size_t)node * 128 + t];
    float sum = (a0 + a1) + (a2 + a3);
    pool[g * 128 + t] = sum / fmaxf((float)(e - s), 1.0f);
}

// ---------------- MLP head: 256 graphs, one block each (pool already holds means) ----------------
__global__ __launch_bounds__(128) void k_mlp(const float* __restrict__ pool,
                                             const float* __restrict__ yex,
                                             const float* __restrict__ lw1, const float* __restrict__ lb1,
                                             const float* __restrict__ lw2, const float* __restrict__ lb2,
                                             const float* __restrict__ lw3, const float* __restrict__ lb3,
                                             const float* __restrict__ lw4, const float* __restrict__ lb4,
                                             float* __restrict__ outp){
    int g = blockIdx.x;
    int t = threadIdx.x;
    __shared__ float z[136];
    __shared__ float z2[128];
    __shared__ float z3[64];
    __shared__ float z4[32];
    z[t] = pool[g * 128 + t];
    if (t < 7) z[128 + t] = yex[g * 7 + t];
    __syncthreads();
    {   // 135 -> 128
        float acc = lb1[t];
        for (int k = 0; k < 135; k++) acc += z[k] * lw1[k * 128 + t];
        z2[t] = gelu_f(acc);
    }
    __syncthreads();
    if (t < 64){   // 128 -> 64
        float acc = lb2[t];
        for (int k = 0; k < 128; k++) acc += z2[k] * lw2[k * 64 + t];
        z3[t] = gelu_f(acc);
    }
    __syncthreads();
    if (t < 32){   // 64 -> 32
        float acc = lb3[t];
        for (int k = 0; k < 64; k++) acc += z3[k] * lw3[k * 32 + t];
        z4[t] = gelu_f(acc);
    }
    __syncthreads();
    if (t < 2){    // 32 -> 2, sigmoid
        float acc = lb4[t];
        for (int k = 0; k < 32; k++) acc += z4[k] * lw4[k * 2 + t];
        outp[g * 2 + t] = 1.0f / (1.0f + expf(-acc));
    }
}

extern "C" void kernel_launch(void* const* d_in, const int* in_sizes, int n_in,
                              void* d_out, int out_size, void* d_ws, size_t ws_size,
                              hipStream_t stream) {
    const float* x     = (const float*)d_in[0];
    const int*   ei    = (const int*)  d_in[1];   // [2, E]: src = ei, dst = ei+E
    const int*   batch = (const int*)  d_in[2];
    const float* yex   = (const float*)d_in[3];
    const float* W1 = (const float*)d_in[4];  const float* b1 = (const float*)d_in[5];
    const float* W2 = (const float*)d_in[6];  const float* b2 = (const float*)d_in[7];
    const float* W3 = (const float*)d_in[8];  const float* b3 = (const float*)d_in[9];
    const float* W4 = (const float*)d_in[10]; const float* b4 = (const float*)d_in[11];
    const float* g1 = (const float*)d_in[12]; const float* be1 = (const float*)d_in[13];
    const float* g2 = (const float*)d_in[14]; const float* be2 = (const float*)d_in[15];
    const float* g3 = (const float*)d_in[16]; const float* be3 = (const float*)d_in[17];
    const float* lw1 = (const float*)d_in[18]; const float* lb1 = (const float*)d_in[19];
    const float* lw2 = (const float*)d_in[20]; const float* lb2 = (const float*)d_in[21];
    const float* lw3 = (const float*)d_in[22]; const float* lb3 = (const float*)d_in[23];
    const float* lw4 = (const float*)d_in[24]; const float* lb4 = (const float*)d_in[25];
    float* out = (float*)d_out;

    // ---- workspace carve (256B-aligned); zero-region first ----
    char* wsb = (char*)d_ws;
    size_t off = 0;
    auto alloc = [&](size_t elems) -> void* {
        void* p = wsb + off;
        off += ((elems * 4 + 255) / 256) * 256;
        return p;
    };
    int*   deg    = (int*)  alloc(NN);
    float* stats  = (float*)alloc(3 * 256);      // layer l: [l*256+c]=sum, [l*256+128+c]=sumsq
    float* agg1   = (float*)alloc(NN);
    size_t zero_bytes = off;
    float* pool   = (float*)alloc(GG * 128);
    int*   rp     = (int*)  alloc(NN + 1);
    int*   cursor = (int*)  alloc(NN);
    float* dis    = (float*)alloc(NN);
    float* invdis = (float*)alloc(NN);
    float* dsum   = (float*)alloc(NN);
    float* xs     = (float*)alloc(NN);
    int*   bsum   = (int*)  alloc(NB_SCAN);
    int*   boff   = (int*)  alloc(NB_SCAN);
    int*   col    = (int*)  alloc(EE);
    float* hbuf   = (float*)alloc((size_t)NN * 128);  // hs (16/32/64ch) and raw h4 (128ch)
    float* abuf   = (float*)alloc((size_t)NN * 64);   // aggregated conv inputs (<=64 ch)

    hipMemsetAsync(d_ws, 0, zero_bytes, stream);

    auto nb = [](long long total){ return (int)((total + 255) / 256); };

    // ---- graph norm precompute (parallel scan; dsum/xs derived in k_apply) ----
    k_deg  <<<nb(EE), 256, 0, stream>>>(ei + EE, deg, EE);
    k_bsum <<<NB_SCAN, 256, 0, stream>>>(deg, bsum, NN);
    k_pscan<<<1, 256, 0, stream>>>(bsum, boff, rp, NB_SCAN, NN);
    k_apply<<<NB_SCAN, 256, 0, stream>>>(deg, boff, rp, cursor, dis, invdis, dsum, x, xs, NN);
    k_fill <<<nb(EE), 256, 0, stream>>>(ei, ei + EE, dis, cursor, dsum, col, EE);

    // ---- layer 1: aggregate xs (C=1), 1->16 linear+gelu (pre-scaled out), stats ----
    k_agg1<<<nb(EE), 256, 0, stream>>>(xs, ei, ei + EE, agg1, EE);
    k_lin1<<<nb((long long)NN * 16), 256, 0, stream>>>(agg1, xs, dis, W1, b1, hbuf, NN);
    k_stats<16><<<128, 256, 0, stream>>>(hbuf, invdis, stats + 0, NN);

    // ---- layer 2: gather hs1 (BN1 inline), 16->32 linear+gelu (pre-scaled), stats ----
    k_gather<16><<<nb((long long)NN * 4), 256, 0, stream>>>(hbuf, rp, col, dis, dsum, stats + 0, g1, be1, abuf, NN);
    k_linT<16, 32, true><<<nb((long long)(NN / 2) * 8), 256, 0, stream>>>(abuf, dis, W2, b2, hbuf, NN);
    k_stats<32><<<128, 256, 0, stream>>>(hbuf, invdis, stats + 256, NN);

    // ---- layer 3: gather hs2 (BN2 inline), 32->64 linear+gelu (pre-scaled), stats ----
    k_gather<32><<<nb((long long)NN * 8), 256, 0, stream>>>(hbuf, rp, col, dis, dsum, stats + 256, g2, be2, abuf, NN);
    k_linT<32, 64, true><<<nb((long long)(NN / 2) * 16), 256, 0, stream>>>(abuf, dis, W3, b3, hbuf, NN);
    k_stats<64><<<128, 256, 0, stream>>>(hbuf, invdis, stats + 512, NN);

    // ---- layer 4: gather hs3 (BN3 inline), 64->128 linear+gelu (raw out), mean pool ----
    k_gather<64><<<nb((long long)NN * 16), 256, 0, stream>>>(hbuf, rp, col, dis, dsum, stats + 512, g3, be3, abuf, NN);
    k_linT<64, 128, false><<<nb((long long)(NN / 2) * 32), 256, 0, stream>>>(abuf, dis, W4, b4, hbuf, NN);
    k_pool<<<GG, 128, 0, stream>>>(hbuf, batch, pool, NN);

    // ---- MLP head ----
    k_mlp<<<GG, 128, 0, stream>>>(pool, yex,
                                  lw1, lb1, lw2, lb2, lw3, lb3, lw4, lb4, out);
}

// Round 9
// 424.980 us; speedup vs baseline: 1.1591x; 1.1591x over previous
//
#include <hip/hip_runtime.h>
#include <math.h>

#define NN 50000
#define EE 800000
#define GG 256
#define NB_SCAN 196   // ceil(50000/256)

__device__ __forceinline__ float gelu_f(float v){
    return 0.5f * v * (1.0f + erff(v * 0.70710678118654752f));
}

// ---------------- degree count over dst ----------------
__global__ __launch_bounds__(256) void k_deg(const int* __restrict__ dst, int* __restrict__ deg, int e){
    int i = blockIdx.x * blockDim.x + threadIdx.x;
    if (i < e) atomicAdd(&deg[dst[i]], 1);
}

// ---------------- scan phase 1: per-block sums ----------------
__global__ __launch_bounds__(256) void k_bsum(const int* __restrict__ deg, int* __restrict__ bsum, int n){
    __shared__ int s[256];
    int t = threadIdx.x;
    int i = blockIdx.x * 256 + t;
    s[t] = (i < n) ? deg[i] : 0;
    __syncthreads();
    for (int off = 128; off > 0; off >>= 1){
        if (t < off) s[t] += s[t + off];
        __syncthreads();
    }
    if (t == 0) bsum[blockIdx.x] = s[0];
}

// ---------------- scan phase 2: single-block scan of partials ----------------
__global__ __launch_bounds__(256) void k_pscan(const int* __restrict__ bsum, int* __restrict__ boff,
                                               int* __restrict__ rp, int nb, int n){
    __shared__ int s[256];
    int t = threadIdx.x;
    int v = (t < nb) ? bsum[t] : 0;
    s[t] = v;
    __syncthreads();
    for (int off = 1; off < 256; off <<= 1){
        int u = (t >= off) ? s[t - off] : 0;
        __syncthreads();
        s[t] += u;
        __syncthreads();
    }
    if (t < nb) boff[t] = s[t] - v;          // exclusive block offset
    if (t == nb - 1) rp[n] = s[t];           // total (= E)
}

// ---------------- scan phase 3: apply + derived per-node arrays ----------------
__global__ __launch_bounds__(256) void k_apply(const int* __restrict__ deg, const int* __restrict__ boff,
                                               int* __restrict__ rp, int* __restrict__ cursor,
                                               float* __restrict__ dis, float* __restrict__ invdis,
                                               const float* __restrict__ x, float* __restrict__ xs, int n){
    __shared__ int s[256];
    int t = threadIdx.x;
    int i = blockIdx.x * 256 + t;
    int d = (i < n) ? deg[i] : 0;
    s[t] = d;
    __syncthreads();
    for (int off = 1; off < 256; off <<= 1){
        int u = (t >= off) ? s[t - off] : 0;
        __syncthreads();
        s[t] += u;
        __syncthreads();
    }
    if (i < n){
        int excl = s[t] - d + boff[blockIdx.x];
        rp[i] = excl;
        cursor[i] = excl;
        float dv = rsqrtf((float)(d + 1));   // +1 self loop
        dis[i] = dv;
        invdis[i] = sqrtf((float)(d + 1));
        xs[i] = dv * x[i];                   // pre-scaled input feature
    }
}

// ---------------- CSR fill: minimal (cursor atomic + col write only) ----------------
__global__ __launch_bounds__(256) void k_fill(const int* __restrict__ src, const int* __restrict__ dst,
                                              int* __restrict__ cursor, int* __restrict__ col, int e){
    int i = blockIdx.x * blockDim.x + threadIdx.x;
    if (i < e){
        int p = atomicAdd(&cursor[dst[i]], 1);
        col[p] = src[i];
    }
}

// ---------------- fused: CSR walk (agg xs, dsum) + layer-1 1->16 linear+GELU+prescale ----------------
// No atomics. Thread per node; adjacent threads read adjacent col segments.
__global__ __launch_bounds__(256) void k_g1l1(const float* __restrict__ xs, const float* __restrict__ dis,
                                              const int* __restrict__ rp, const int* __restrict__ col,
                                              const float* __restrict__ W, const float* __restrict__ bias,
                                              float* __restrict__ dsum, float* __restrict__ hs, int n){
    int node = blockIdx.x * 256 + threadIdx.x;
    if (node >= n) return;
    int beg = rp[node], end = rp[node + 1];
    float a0 = 0.f, a1 = 0.f, d0 = 0.f, d1 = 0.f;
    int j = beg;
    for (; j + 1 < end; j += 2){
        int c0 = col[j], c1 = col[j + 1];
        a0 += xs[c0]; d0 += dis[c0];
        a1 += xs[c1]; d1 += dis[c1];
    }
    if (j < end){ int c = col[j]; a0 += xs[c]; d0 += dis[c]; }
    float dn = dis[node];
    dsum[node] = d0 + d1 + dn;               // sum of dis over neighbors + self
    float a = dn * (a0 + a1 + xs[node]);     // raw conv1 pre-activation basis
    float4* o = (float4*)(hs + (size_t)node * 16);
#pragma unroll
    for (int u = 0; u < 4; u++){
        float4 r;
        r.x = gelu_f(bias[u*4+0] + a * W[u*4+0]) * dn;
        r.y = gelu_f(bias[u*4+1] + a * W[u*4+1]) * dn;
        r.z = gelu_f(bias[u*4+2] + a * W[u*4+2]) * dn;
        r.w = gelu_f(bias[u*4+3] + a * W[u*4+3]) * dn;
        o[u] = r;
    }
}

// ---------------- gather of pre-scaled hs with inline BN affine (float4, 4-edge unroll) ----------------
// out[d] = dis_d * ( sc * (sum_{s in N(d)} hs[s] + hs[d]) + sh * dsum[d] )
template<int C>
__global__ __launch_bounds__(256) void k_gather(const float* __restrict__ hs, const int* __restrict__ rp,
                                                const int* __restrict__ col, const float* __restrict__ dis,
                                                const float* __restrict__ dsum, const float* __restrict__ stat,
                                                const float* __restrict__ gamma, const float* __restrict__ beta,
                                                float* __restrict__ outp, int n){
    constexpr int TPN = C / 4;
    int i = blockIdx.x * 256 + threadIdx.x;
    int node = i / TPN, q = i % TPN;
    if (node >= n) return;
    int c0 = q * 4;
    const float invn = 1.0f / (float)NN;
    float scv[4], shv[4];
#pragma unroll
    for (int u = 0; u < 4; u++){
        float mean = stat[c0 + u] * invn;
        float var  = stat[128 + c0 + u] * invn - mean * mean;
        float sc   = gamma[c0 + u] * rsqrtf(var + 1e-5f);
        scv[u] = sc;
        shv[u] = beta[c0 + u] - mean * sc;
    }
    const float4* h4 = (const float4*)hs;
    int beg = rp[node], end = rp[node + 1];
    float a0 = 0.f, a1 = 0.f, a2 = 0.f, a3 = 0.f;
    float b0 = 0.f, b1 = 0.f, b2 = 0.f, b3 = 0.f;
    int j = beg;
    for (; j + 3 < end; j += 4){
        int i0 = col[j], i1 = col[j+1], i2 = col[j+2], i3 = col[j+3];
        float4 v0 = h4[i0 * TPN + q];
        float4 v1 = h4[i1 * TPN + q];
        float4 v2 = h4[i2 * TPN + q];
        float4 v3 = h4[i3 * TPN + q];
        a0 += v0.x; a1 += v0.y; a2 += v0.z; a3 += v0.w;
        b0 += v1.x; b1 += v1.y; b2 += v1.z; b3 += v1.w;
        a0 += v2.x; a1 += v2.y; a2 += v2.z; a3 += v2.w;
        b0 += v3.x; b1 += v3.y; b2 += v3.z; b3 += v3.w;
    }
    for (; j < end; j++){
        float4 v = h4[col[j] * TPN + q];
        a0 += v.x; a1 += v.y; a2 += v.z; a3 += v.w;
    }
    float4 vs = h4[node * TPN + q];    // self loop (weight 1 in pre-scaled space)
    a0 += vs.x; a1 += vs.y; a2 += vs.z; a3 += vs.w;
    a0 += b0; a1 += b1; a2 += b2; a3 += b3;
    float dn = dis[node];
    float dsm = dsum[node];
    float4 r = make_float4((a0 * scv[0] + shv[0] * dsm) * dn,
                           (a1 * scv[1] + shv[1] * dsm) * dn,
                           (a2 * scv[2] + shv[2] * dsm) * dn,
                           (a3 * scv[3] + shv[3] * dsm) * dn);
    ((float4*)outp)[node * TPN + q] = r;
}

// ---------------- dense linear + bias + GELU: 2 nodes x 4 channels per thread ----------------
// SCALE: multiply output by dis[node] (pre-scale for the next gather). Layer 4: SCALE=false.
template<int CIN, int COUT, bool SCALE>
__global__ __launch_bounds__(256) void k_linT(const float* __restrict__ xin, const float* __restrict__ dis,
                                              const float* __restrict__ W,
                                              const float* __restrict__ bias, float* __restrict__ outp, int n){
    constexpr int QC = COUT / 4;      // float4 channel groups
    constexpr int K4 = CIN / 4;       // float4 K groups
    int i = blockIdx.x * 256 + threadIdx.x;
    int pair = i / QC, q = i % QC;
    int n0 = pair * 2;                 // NN % 2 == 0
    if (n0 >= n) return;
    const float4* xa = (const float4*)(xin + (size_t)n0 * CIN);
    const float4* xb = (const float4*)(xin + (size_t)(n0 + 1) * CIN);
    const float4* Wq = (const float4*)W + q;      // row k at Wq[k * QC]
    float4 bb = ((const float4*)bias)[q];
    float aA0 = bb.x, aA1 = bb.y, aA2 = bb.z, aA3 = bb.w;
    float aB0 = bb.x, aB1 = bb.y, aB2 = bb.z, aB3 = bb.w;
#pragma unroll 1
    for (int k4 = 0; k4 < K4; k4++){
        float4 xA = xa[k4];
        float4 xB = xb[k4];
        float4 w0 = Wq[(k4 * 4 + 0) * QC];
        float4 w1 = Wq[(k4 * 4 + 1) * QC];
        float4 w2 = Wq[(k4 * 4 + 2) * QC];
        float4 w3 = Wq[(k4 * 4 + 3) * QC];
        aA0 += xA.x*w0.x + xA.y*w1.x + xA.z*w2.x + xA.w*w3.x;
        aA1 += xA.x*w0.y + xA.y*w1.y + xA.z*w2.y + xA.w*w3.y;
        aA2 += xA.x*w0.z + xA.y*w1.z + xA.z*w2.z + xA.w*w3.z;
        aA3 += xA.x*w0.w + xA.y*w1.w + xA.z*w2.w + xA.w*w3.w;
        aB0 += xB.x*w0.x + xB.y*w1.x + xB.z*w2.x + xB.w*w3.x;
        aB1 += xB.x*w0.y + xB.y*w1.y + xB.z*w2.y + xB.w*w3.y;
        aB2 += xB.x*w0.z + xB.y*w1.z + xB.z*w2.z + xB.w*w3.z;
        aB3 += xB.x*w0.w + xB.y*w1.w + xB.z*w2.w + xB.w*w3.w;
    }
    float sA = SCALE ? dis[n0] : 1.0f;
    float sB = SCALE ? dis[n0 + 1] : 1.0f;
    float4* o4 = (float4*)outp;
    o4[(size_t)n0 * QC + q]       = make_float4(gelu_f(aA0)*sA, gelu_f(aA1)*sA, gelu_f(aA2)*sA, gelu_f(aA3)*sA);
    o4[(size_t)(n0 + 1) * QC + q] = make_float4(gelu_f(aB0)*sB, gelu_f(aB1)*sB, gelu_f(aB2)*sB, gelu_f(aB3)*sB);
}

// ---------------- BN stats over raw h (de-scale pre-scaled hs by invdis) ----------------
template<int C>
__global__ __launch_bounds__(256) void k_stats(const float* __restrict__ hs, const float* __restrict__ invdis,
                                               float* __restrict__ stat, int n){
    constexpr int REP = 256 / C;
    int t = threadIdx.x;
    int rep = t / C;
    int c = t % C;
    float s = 0.f, q = 0.f;
    for (int row = blockIdx.x * REP + rep; row < n; row += gridDim.x * REP){
        float v = hs[(long long)row * C + c] * invdis[row];
        s += v; q += v * v;
    }
    __shared__ float ss[256], sq[256];
    ss[t] = s; sq[t] = q;
    __syncthreads();
    for (int off = 128; off >= C; off >>= 1){
        if (t < off){ ss[t] += ss[t + off]; sq[t] += sq[t + off]; }
        __syncthreads();
    }
    if (t < C){
        atomicAdd(&stat[t], ss[t]);
        atomicAdd(&stat[128 + t], sq[t]);
    }
}

// ---------------- mean-pool: one block per graph, binary search sorted batch, no atomics ----------------
__global__ __launch_bounds__(128) void k_pool(const float* __restrict__ h4, const int* __restrict__ batch,
                                              float* __restrict__ pool, int n){
    int g = blockIdx.x;
    int t = threadIdx.x;
    int lo = 0, hi = n;
    while (lo < hi){ int mid = (lo + hi) >> 1; if (batch[mid] < g) lo = mid + 1; else hi = mid; }
    int s = lo;
    hi = n;
    while (lo < hi){ int mid = (lo + hi) >> 1; if (batch[mid] < g + 1) lo = mid + 1; else hi = mid; }
    int e = lo;
    float a0 = 0.f, a1 = 0.f, a2 = 0.f, a3 = 0.f;
    int node = s;
    for (; node + 3 < e; node += 4){
        a0 += h4[(size_t)(node + 0) * 128 + t];
        a1 += h4[(size_t)(node + 1) * 128 + t];
        a2 += h4[(size_t)(node + 2) * 128 + t];
        a3 += h4[(size_t)(node + 3) * 128 + t];
    }
    for (; node < e; node++) a0 += h4[(size_t)node * 128 + t];
    float sum = (a0 + a1) + (a2 + a3);
    pool[g * 128 + t] = sum / fmaxf((float)(e - s), 1.0f);
}

// ---------------- MLP head: 256 graphs, one block each (pool already holds means) ----------------
__global__ __launch_bounds__(128) void k_mlp(const float* __restrict__ pool,
                                             const float* __restrict__ yex,
                                             const float* __restrict__ lw1, const float* __restrict__ lb1,
                                             const float* __restrict__ lw2, const float* __restrict__ lb2,
                                             const float* __restrict__ lw3, const float* __restrict__ lb3,
                                             const float* __restrict__ lw4, const float* __restrict__ lb4,
                                             float* __restrict__ outp){
    int g = blockIdx.x;
    int t = threadIdx.x;
    __shared__ float z[136];
    __shared__ float z2[128];
    __shared__ float z3[64];
    __shared__ float z4[32];
    z[t] = pool[g * 128 + t];
    if (t < 7) z[128 + t] = yex[g * 7 + t];
    __syncthreads();
    {   // 135 -> 128
        float acc = lb1[t];
        for (int k = 0; k < 135; k++) acc += z[k] * lw1[k * 128 + t];
        z2[t] = gelu_f(acc);
    }
    __syncthreads();
    if (t < 64){   // 128 -> 64
        float acc = lb2[t];
        for (int k = 0; k < 128; k++) acc += z2[k] * lw2[k * 64 + t];
        z3[t] = gelu_f(acc);
    }
    __syncthreads();
    if (t < 32){   // 64 -> 32
        float acc = lb3[t];
        for (int k = 0; k < 64; k++) acc += z3[k] * lw3[k * 32 + t];
        z4[t] = gelu_f(acc);
    }
    __syncthreads();
    if (t < 2){    // 32 -> 2, sigmoid
        float acc = lb4[t];
        for (int k = 0; k < 32; k++) acc += z4[k] * lw4[k * 2 + t];
        outp[g * 2 + t] = 1.0f / (1.0f + expf(-acc));
    }
}

extern "C" void kernel_launch(void* const* d_in, const int* in_sizes, int n_in,
                              void* d_out, int out_size, void* d_ws, size_t ws_size,
                              hipStream_t stream) {
    const float* x     = (const float*)d_in[0];
    const int*   ei    = (const int*)  d_in[1];   // [2, E]: src = ei, dst = ei+E
    const int*   batch = (const int*)  d_in[2];
    const float* yex   = (const float*)d_in[3];
    const float* W1 = (const float*)d_in[4];  const float* b1 = (const float*)d_in[5];
    const float* W2 = (const float*)d_in[6];  const float* b2 = (const float*)d_in[7];
    const float* W3 = (const float*)d_in[8];  const float* b3 = (const float*)d_in[9];
    const float* W4 = (const float*)d_in[10]; const float* b4 = (const float*)d_in[11];
    const float* g1 = (const float*)d_in[12]; const float* be1 = (const float*)d_in[13];
    const float* g2 = (const float*)d_in[14]; const float* be2 = (const float*)d_in[15];
    const float* g3 = (const float*)d_in[16]; const float* be3 = (const float*)d_in[17];
    const float* lw1 = (const float*)d_in[18]; const float* lb1 = (const float*)d_in[19];
    const float* lw2 = (const float*)d_in[20]; const float* lb2 = (const float*)d_in[21];
    const float* lw3 = (const float*)d_in[22]; const float* lb3 = (const float*)d_in[23];
    const float* lw4 = (const float*)d_in[24]; const float* lb4 = (const float*)d_in[25];
    float* out = (float*)d_out;

    // ---- workspace carve (256B-aligned); zero-region first ----
    char* wsb = (char*)d_ws;
    size_t off = 0;
    auto alloc = [&](size_t elems) -> void* {
        void* p = wsb + off;
        off += ((elems * 4 + 255) / 256) * 256;
        return p;
    };
    int*   deg    = (int*)  alloc(NN);
    float* stats  = (float*)alloc(3 * 256);      // layer l: [l*256+c]=sum, [l*256+128+c]=sumsq
    size_t zero_bytes = off;
    float* pool   = (float*)alloc(GG * 128);
    int*   rp     = (int*)  alloc(NN + 1);
    int*   cursor = (int*)  alloc(NN);
    float* dis    = (float*)alloc(NN);
    float* invdis = (float*)alloc(NN);
    float* dsum   = (float*)alloc(NN);
    float* xs     = (float*)alloc(NN);
    int*   bsum   = (int*)  alloc(NB_SCAN);
    int*   boff   = (int*)  alloc(NB_SCAN);
    int*   col    = (int*)  alloc(EE);
    float* hbuf   = (float*)alloc((size_t)NN * 128);  // hs (16/32/64ch) and raw h4 (128ch)
    float* abuf   = (float*)alloc((size_t)NN * 64);   // aggregated conv inputs (<=64 ch)

    hipMemsetAsync(d_ws, 0, zero_bytes, stream);

    auto nb = [](long long total){ return (int)((total + 255) / 256); };

    // ---- graph norm precompute (parallel scan) ----
    k_deg  <<<nb(EE), 256, 0, stream>>>(ei + EE, deg, EE);
    k_bsum <<<NB_SCAN, 256, 0, stream>>>(deg, bsum, NN);
    k_pscan<<<1, 256, 0, stream>>>(bsum, boff, rp, NB_SCAN, NN);
    k_apply<<<NB_SCAN, 256, 0, stream>>>(deg, boff, rp, cursor, dis, invdis, x, xs, NN);
    k_fill <<<nb(EE), 256, 0, stream>>>(ei, ei + EE, cursor, col, EE);

    // ---- layer 1: fused CSR-walk (agg xs + dsum) + 1->16 linear+gelu (pre-scaled), stats ----
    k_g1l1<<<NB_SCAN, 256, 0, stream>>>(xs, dis, rp, col, W1, b1, dsum, hbuf, NN);
    k_stats<16><<<128, 256, 0, stream>>>(hbuf, invdis, stats + 0, NN);

    // ---- layer 2: gather hs1 (BN1 inline), 16->32 linear+gelu (pre-scaled), stats ----
    k_gather<16><<<nb((long long)NN * 4), 256, 0, stream>>>(hbuf, rp, col, dis, dsum, stats + 0, g1, be1, abuf, NN);
    k_linT<16, 32, true><<<nb((long long)(NN / 2) * 8), 256, 0, stream>>>(abuf, dis, W2, b2, hbuf, NN);
    k_stats<32><<<128, 256, 0, stream>>>(hbuf, invdis, stats + 256, NN);

    // ---- layer 3: gather hs2 (BN2 inline), 32->64 linear+gelu (pre-scaled), stats ----
    k_gather<32><<<nb((long long)NN * 8), 256, 0, stream>>>(hbuf, rp, col, dis, dsum, stats + 256, g2, be2, abuf, NN);
    k_linT<32, 64, true><<<nb((long long)(NN / 2) * 16), 256, 0, stream>>>(abuf, dis, W3, b3, hbuf, NN);
    k_stats<64><<<128, 256, 0, stream>>>(hbuf, invdis, stats + 512, NN);

    // ---- layer 4: gather hs3 (BN3 inline), 64->128 linear+gelu (raw out), mean pool ----
    k_gather<64><<<nb((long long)NN * 16), 256, 0, stream>>>(hbuf, rp, col, dis, dsum, stats + 512, g3, be3, abuf, NN);
    k_linT<64, 128, false><<<nb((long long)(NN / 2) * 32), 256, 0, stream>>>(abuf, dis, W4, b4, hbuf, NN);
    k_pool<<<GG, 128, 0, stream>>>(hbuf, batch, pool, NN);

    // ---- MLP head ----
    k_mlp<<<GG, 128, 0, stream>>>(pool, yex,
                                  lw1, lb1, lw2, lb2, lw3, lb3, lw4, lb4, out);
}

// Round 10
// 374.355 us; speedup vs baseline: 1.3159x; 1.1352x over previous
//
#include <hip/hip_runtime.h>
#include <math.h>

#define NN 50000
#define EE 800000
#define GG 256
#define NPB 100          // nodes per bucket
#define NBUCK 500        // NN / NPB exactly
#define EPB 4096         // edges per block chunk (hist/scatter)
#define NEB 196          // ceil(EE/EPB)
#define NB_NODE 196      // ceil(NN/256) node-parallel grids

__device__ __forceinline__ float gelu_f(float v){
    return 0.5f * v * (1.0f + erff(v * 0.70710678118654752f));
}

// ---------------- bucket histogram of dst (LDS-privatized, padded global) ----------------
__global__ __launch_bounds__(256) void k_hist(const int* __restrict__ dst, int* __restrict__ bucket_cnt_p, int e){
    __shared__ int hist[512];
    int t = threadIdx.x;
    int start = blockIdx.x * EPB;
    for (int k = t; k < 512; k += 256) hist[k] = 0;
    __syncthreads();
#pragma unroll
    for (int k = 0; k < EPB / 256; k++){
        int idx = start + k * 256 + t;
        if (idx < e) atomicAdd(&hist[dst[idx] / NPB], 1);
    }
    __syncthreads();
    for (int k = t; k < NBUCK; k += 256){
        int h = hist[k];
        if (h) atomicAdd(&bucket_cnt_p[k * 16], h);   // *16: one cache line per bucket
    }
}

// ---------------- scan bucket counts -> offsets + scatter cursors ----------------
__global__ __launch_bounds__(512) void k_bscan(const int* __restrict__ bucket_cnt_p,
                                               int* __restrict__ bucket_off, int* __restrict__ cursor_p){
    __shared__ int s[512];
    int t = threadIdx.x;
    int v = (t < NBUCK) ? bucket_cnt_p[t * 16] : 0;
    s[t] = v;
    __syncthreads();
    for (int off = 1; off < 512; off <<= 1){
        int u = (t >= off) ? s[t - off] : 0;
        __syncthreads();
        s[t] += u;
        __syncthreads();
    }
    if (t < NBUCK){
        int ex = s[t] - v;
        bucket_off[t] = ex;
        cursor_p[t * 16] = ex;
    }
}

// ---------------- partition (src,dst) pairs into bucket-contiguous ebuf ----------------
// Register-stash edges; per-(block,bucket) one padded global atomic reserves a
// contiguous range, so writes land in ~64B runs instead of random 4B scatter.
__global__ __launch_bounds__(256) void k_scatter(const int* __restrict__ src, const int* __restrict__ dst,
                                                 int* __restrict__ cursor_p, int2* __restrict__ ebuf, int e){
    __shared__ int hist[512], base[512];
    int t = threadIdx.x;
    int start = blockIdx.x * EPB;
    for (int k = t; k < 512; k += 256) hist[k] = 0;
    __syncthreads();
    int ss[EPB / 256], dd[EPB / 256], bb[EPB / 256];
    int cntl = 0;
#pragma unroll
    for (int k = 0; k < EPB / 256; k++){
        int idx = start + k * 256 + t;
        if (idx < e){
            int s_ = src[idx], d_ = dst[idx];
            int b_ = d_ / NPB;
            ss[cntl] = s_; dd[cntl] = d_; bb[cntl] = b_;
            atomicAdd(&hist[b_], 1);
            cntl++;
        }
    }
    __syncthreads();
    for (int k = t; k < NBUCK; k += 256){
        int h = hist[k];
        base[k] = h ? atomicAdd(&cursor_p[k * 16], h) : 0;
    }
    __syncthreads();
    for (int k = t; k < 512; k += 256) hist[k] = 0;
    __syncthreads();
    for (int k = 0; k < cntl; k++){
        int b_ = bb[k];
        int pos = base[b_] + atomicAdd(&hist[b_], 1);
        ebuf[pos] = make_int2(ss[k], dd[k]);
    }
}

// ---------------- per-bucket CSR finalize: node deg/rp/col + dis/invdis/xs (LDS only) ----------------
__global__ __launch_bounds__(256) void k_build(const int2* __restrict__ ebuf,
                                               const int* __restrict__ bucket_cnt_p,
                                               const int* __restrict__ bucket_off,
                                               int* __restrict__ rp, int* __restrict__ col,
                                               float* __restrict__ dis, float* __restrict__ invdis,
                                               const float* __restrict__ x, float* __restrict__ xs, int n){
    int b = blockIdx.x;
    int t = threadIdx.x;
    int nbase = b * NPB;
    int eoff = bucket_off[b];
    int ecnt = bucket_cnt_p[b * 16];
    __shared__ int cnt[128], excl[128], cnt2[128], s[128];
    if (t < 128){ cnt[t] = 0; cnt2[t] = 0; }
    __syncthreads();
    for (int j = t; j < ecnt; j += 256)
        atomicAdd(&cnt[ebuf[eoff + j].y - nbase], 1);
    __syncthreads();
    int v = (t < 128) ? cnt[t] : 0;
    if (t < 128) s[t] = v;
    __syncthreads();
    for (int off = 1; off < 128; off <<= 1){
        int u = (t < 128 && t >= off) ? s[t - off] : 0;
        __syncthreads();
        if (t < 128) s[t] += u;
        __syncthreads();
    }
    if (t < 128) excl[t] = s[t] - v;
    __syncthreads();
    if (t < NPB){
        int node = nbase + t;      // NBUCK*NPB == NN exactly
        int dgg = cnt[t];
        rp[node] = eoff + excl[t];
        float dv = rsqrtf((float)(dgg + 1));   // +1 self loop
        dis[node] = dv;
        invdis[node] = sqrtf((float)(dgg + 1));
        xs[node] = dv * x[node];
    }
    if (b == NBUCK - 1 && t == 0) rp[n] = eoff + ecnt;   // == E
    __syncthreads();
    for (int j = t; j < ecnt; j += 256){
        int2 e2 = ebuf[eoff + j];
        int li = e2.y - nbase;
        int p = eoff + excl[li] + atomicAdd(&cnt2[li], 1);
        col[p] = e2.x;             // 6.4KB window per bucket -> full line reuse
    }
}

// ---------------- fused: CSR walk (agg xs, dsum) + layer-1 1->16 linear+GELU+prescale ----------------
__global__ __launch_bounds__(256) void k_g1l1(const float* __restrict__ xs, const float* __restrict__ dis,
                                              const int* __restrict__ rp, const int* __restrict__ col,
                                              const float* __restrict__ W, const float* __restrict__ bias,
                                              float* __restrict__ dsum, float* __restrict__ hs, int n){
    int node = blockIdx.x * 256 + threadIdx.x;
    if (node >= n) return;
    int beg = rp[node], end = rp[node + 1];
    float a0 = 0.f, a1 = 0.f, d0 = 0.f, d1 = 0.f;
    int j = beg;
    for (; j + 1 < end; j += 2){
        int c0 = col[j], c1 = col[j + 1];
        a0 += xs[c0]; d0 += dis[c0];
        a1 += xs[c1]; d1 += dis[c1];
    }
    if (j < end){ int c = col[j]; a0 += xs[c]; d0 += dis[c]; }
    float dn = dis[node];
    dsum[node] = d0 + d1 + dn;
    float a = dn * (a0 + a1 + xs[node]);
    float4* o = (float4*)(hs + (size_t)node * 16);
#pragma unroll
    for (int u = 0; u < 4; u++){
        float4 r;
        r.x = gelu_f(bias[u*4+0] + a * W[u*4+0]) * dn;
        r.y = gelu_f(bias[u*4+1] + a * W[u*4+1]) * dn;
        r.z = gelu_f(bias[u*4+2] + a * W[u*4+2]) * dn;
        r.w = gelu_f(bias[u*4+3] + a * W[u*4+3]) * dn;
        o[u] = r;
    }
}

// ---------------- gather of pre-scaled hs with inline BN affine (float4, 4-edge unroll) ----------------
template<int C>
__global__ __launch_bounds__(256) void k_gather(const float* __restrict__ hs, const int* __restrict__ rp,
                                                const int* __restrict__ col, const float* __restrict__ dis,
                                                const float* __restrict__ dsum, const float* __restrict__ stat,
                                                const float* __restrict__ gamma, const float* __restrict__ beta,
                                                float* __restrict__ outp, int n){
    constexpr int TPN = C / 4;
    int i = blockIdx.x * 256 + threadIdx.x;
    int node = i / TPN, q = i % TPN;
    if (node >= n) return;
    int c0 = q * 4;
    const float invn = 1.0f / (float)NN;
    float scv[4], shv[4];
#pragma unroll
    for (int u = 0; u < 4; u++){
        float mean = stat[c0 + u] * invn;
        float var  = stat[128 + c0 + u] * invn - mean * mean;
        float sc   = gamma[c0 + u] * rsqrtf(var + 1e-5f);
        scv[u] = sc;
        shv[u] = beta[c0 + u] - mean * sc;
    }
    const float4* h4 = (const float4*)hs;
    int beg = rp[node], end = rp[node + 1];
    float a0 = 0.f, a1 = 0.f, a2 = 0.f, a3 = 0.f;
    float b0 = 0.f, b1 = 0.f, b2 = 0.f, b3 = 0.f;
    int j = beg;
    for (; j + 3 < end; j += 4){
        int i0 = col[j], i1 = col[j+1], i2 = col[j+2], i3 = col[j+3];
        float4 v0 = h4[i0 * TPN + q];
        float4 v1 = h4[i1 * TPN + q];
        float4 v2 = h4[i2 * TPN + q];
        float4 v3 = h4[i3 * TPN + q];
        a0 += v0.x; a1 += v0.y; a2 += v0.z; a3 += v0.w;
        b0 += v1.x; b1 += v1.y; b2 += v1.z; b3 += v1.w;
        a0 += v2.x; a1 += v2.y; a2 += v2.z; a3 += v2.w;
        b0 += v3.x; b1 += v3.y; b2 += v3.z; b3 += v3.w;
    }
    for (; j < end; j++){
        float4 v = h4[col[j] * TPN + q];
        a0 += v.x; a1 += v.y; a2 += v.z; a3 += v.w;
    }
    float4 vs = h4[node * TPN + q];    // self loop (weight 1 in pre-scaled space)
    a0 += vs.x; a1 += vs.y; a2 += vs.z; a3 += vs.w;
    a0 += b0; a1 += b1; a2 += b2; a3 += b3;
    float dn = dis[node];
    float dsm = dsum[node];
    float4 r = make_float4((a0 * scv[0] + shv[0] * dsm) * dn,
                           (a1 * scv[1] + shv[1] * dsm) * dn,
                           (a2 * scv[2] + shv[2] * dsm) * dn,
                           (a3 * scv[3] + shv[3] * dsm) * dn);
    ((float4*)outp)[node * TPN + q] = r;
}

// ---------------- dense linear + bias + GELU: 2 nodes x 4 channels per thread ----------------
template<int CIN, int COUT, bool SCALE>
__global__ __launch_bounds__(256) void k_linT(const float* __restrict__ xin, const float* __restrict__ dis,
                                              const float* __restrict__ W,
                                              const float* __restrict__ bias, float* __restrict__ outp, int n){
    constexpr int QC = COUT / 4;
    constexpr int K4 = CIN / 4;
    int i = blockIdx.x * 256 + threadIdx.x;
    int pair = i / QC, q = i % QC;
    int n0 = pair * 2;
    if (n0 >= n) return;
    const float4* xa = (const float4*)(xin + (size_t)n0 * CIN);
    const float4* xb = (const float4*)(xin + (size_t)(n0 + 1) * CIN);
    const float4* Wq = (const float4*)W + q;
    float4 bb = ((const float4*)bias)[q];
    float aA0 = bb.x, aA1 = bb.y, aA2 = bb.z, aA3 = bb.w;
    float aB0 = bb.x, aB1 = bb.y, aB2 = bb.z, aB3 = bb.w;
#pragma unroll 1
    for (int k4 = 0; k4 < K4; k4++){
        float4 xA = xa[k4];
        float4 xB = xb[k4];
        float4 w0 = Wq[(k4 * 4 + 0) * QC];
        float4 w1 = Wq[(k4 * 4 + 1) * QC];
        float4 w2 = Wq[(k4 * 4 + 2) * QC];
        float4 w3 = Wq[(k4 * 4 + 3) * QC];
        aA0 += xA.x*w0.x + xA.y*w1.x + xA.z*w2.x + xA.w*w3.x;
        aA1 += xA.x*w0.y + xA.y*w1.y + xA.z*w2.y + xA.w*w3.y;
        aA2 += xA.x*w0.z + xA.y*w1.z + xA.z*w2.z + xA.w*w3.z;
        aA3 += xA.x*w0.w + xA.y*w1.w + xA.z*w2.w + xA.w*w3.w;
        aB0 += xB.x*w0.x + xB.y*w1.x + xB.z*w2.x + xB.w*w3.x;
        aB1 += xB.x*w0.y + xB.y*w1.y + xB.z*w2.y + xB.w*w3.y;
        aB2 += xB.x*w0.z + xB.y*w1.z + xB.z*w2.z + xB.w*w3.z;
        aB3 += xB.x*w0.w + xB.y*w1.w + xB.z*w2.w + xB.w*w3.w;
    }
    float sA = SCALE ? dis[n0] : 1.0f;
    float sB = SCALE ? dis[n0 + 1] : 1.0f;
    float4* o4 = (float4*)outp;
    o4[(size_t)n0 * QC + q]       = make_float4(gelu_f(aA0)*sA, gelu_f(aA1)*sA, gelu_f(aA2)*sA, gelu_f(aA3)*sA);
    o4[(size_t)(n0 + 1) * QC + q] = make_float4(gelu_f(aB0)*sB, gelu_f(aB1)*sB, gelu_f(aB2)*sB, gelu_f(aB3)*sB);
}

// ---------------- BN stats over raw h (de-scale pre-scaled hs by invdis) ----------------
template<int C>
__global__ __launch_bounds__(256) void k_stats(const float* __restrict__ hs, const float* __restrict__ invdis,
                                               float* __restrict__ stat, int n){
    constexpr int REP = 256 / C;
    int t = threadIdx.x;
    int rep = t / C;
    int c = t % C;
    float s = 0.f, q = 0.f;
    for (int row = blockIdx.x * REP + rep; row < n; row += gridDim.x * REP){
        float v = hs[(long long)row * C + c] * invdis[row];
        s += v; q += v * v;
    }
    __shared__ float ss[256], sq[256];
    ss[t] = s; sq[t] = q;
    __syncthreads();
    for (int off = 128; off >= C; off >>= 1){
        if (t < off){ ss[t] += ss[t + off]; sq[t] += sq[t + off]; }
        __syncthreads();
    }
    if (t < C){
        atomicAdd(&stat[t], ss[t]);
        atomicAdd(&stat[128 + t], sq[t]);
    }
}

// ---------------- mean-pool: one block per graph, binary search sorted batch, no atomics ----------------
__global__ __launch_bounds__(128) void k_pool(const float* __restrict__ h4, const int* __restrict__ batch,
                                              float* __restrict__ pool, int n){
    int g = blockIdx.x;
    int t = threadIdx.x;
    int lo = 0, hi = n;
    while (lo < hi){ int mid = (lo + hi) >> 1; if (batch[mid] < g) lo = mid + 1; else hi = mid; }
    int s = lo;
    hi = n;
    while (lo < hi){ int mid = (lo + hi) >> 1; if (batch[mid] < g + 1) lo = mid + 1; else hi = mid; }
    int e = lo;
    float a0 = 0.f, a1 = 0.f, a2 = 0.f, a3 = 0.f;
    int node = s;
    for (; node + 3 < e; node += 4){
        a0 += h4[(size_t)(node + 0) * 128 + t];
        a1 += h4[(size_t)(node + 1) * 128 + t];
        a2 += h4[(size_t)(node + 2) * 128 + t];
        a3 += h4[(size_t)(node + 3) * 128 + t];
    }
    for (; node < e; node++) a0 += h4[(size_t)node * 128 + t];
    float sum = (a0 + a1) + (a2 + a3);
    pool[g * 128 + t] = sum / fmaxf((float)(e - s), 1.0f);
}

// ---------------- MLP head: 256 graphs, one block each ----------------
__global__ __launch_bounds__(128) void k_mlp(const float* __restrict__ pool,
                                             const float* __restrict__ yex,
                                             const float* __restrict__ lw1, const float* __restrict__ lb1,
                                             const float* __restrict__ lw2, const float* __restrict__ lb2,
                                             const float* __restrict__ lw3, const float* __restrict__ lb3,
                                             const float* __restrict__ lw4, const float* __restrict__ lb4,
                                             float* __restrict__ outp){
    int g = blockIdx.x;
    int t = threadIdx.x;
    __shared__ float z[136];
    __shared__ float z2[128];
    __shared__ float z3[64];
    __shared__ float z4[32];
    z[t] = pool[g * 128 + t];
    if (t < 7) z[128 + t] = yex[g * 7 + t];
    __syncthreads();
    {   // 135 -> 128
        float acc = lb1[t];
        for (int k = 0; k < 135; k++) acc += z[k] * lw1[k * 128 + t];
        z2[t] = gelu_f(acc);
    }
    __syncthreads();
    if (t < 64){   // 128 -> 64
        float acc = lb2[t];
        for (int k = 0; k < 128; k++) acc += z2[k] * lw2[k * 64 + t];
        z3[t] = gelu_f(acc);
    }
    __syncthreads();
    if (t < 32){   // 64 -> 32
        float acc = lb3[t];
        for (int k = 0; k < 64; k++) acc += z3[k] * lw3[k * 32 + t];
        z4[t] = gelu_f(acc);
    }
    __syncthreads();
    if (t < 2){    // 32 -> 2, sigmoid
        float acc = lb4[t];
        for (int k = 0; k < 32; k++) acc += z4[k] * lw4[k * 2 + t];
        outp[g * 2 + t] = 1.0f / (1.0f + expf(-acc));
    }
}

extern "C" void kernel_launch(void* const* d_in, const int* in_sizes, int n_in,
                              void* d_out, int out_size, void* d_ws, size_t ws_size,
                              hipStream_t stream) {
    const float* x     = (const float*)d_in[0];
    const int*   ei    = (const int*)  d_in[1];   // [2, E]: src = ei, dst = ei+E
    const int*   batch = (const int*)  d_in[2];
    const float* yex   = (const float*)d_in[3];
    const float* W1 = (const float*)d_in[4];  const float* b1 = (const float*)d_in[5];
    const float* W2 = (const float*)d_in[6];  const float* b2 = (const float*)d_in[7];
    const float* W3 = (const float*)d_in[8];  const float* b3 = (const float*)d_in[9];
    const float* W4 = (const float*)d_in[10]; const float* b4 = (const float*)d_in[11];
    const float* g1 = (const float*)d_in[12]; const float* be1 = (const float*)d_in[13];
    const float* g2 = (const float*)d_in[14]; const float* be2 = (const float*)d_in[15];
    const float* g3 = (const float*)d_in[16]; const float* be3 = (const float*)d_in[17];
    const float* lw1 = (const float*)d_in[18]; const float* lb1 = (const float*)d_in[19];
    const float* lw2 = (const float*)d_in[20]; const float* lb2 = (const float*)d_in[21];
    const float* lw3 = (const float*)d_in[22]; const float* lb3 = (const float*)d_in[23];
    const float* lw4 = (const float*)d_in[24]; const float* lb4 = (const float*)d_in[25];
    float* out = (float*)d_out;

    // ---- workspace carve (256B-aligned); zero-region first ----
    char* wsb = (char*)d_ws;
    size_t off = 0;
    auto alloc = [&](size_t elems) -> void* {
        void* p = wsb + off;
        off += ((elems * 4 + 255) / 256) * 256;
        return p;
    };
    float* stats        = (float*)alloc(3 * 256);      // layer l: [l*256+c]=sum, [+128]=sumsq
    int*   bucket_cnt_p = (int*)  alloc(NBUCK * 16);   // padded: 1 line per bucket
    size_t zero_bytes = off;
    int*   bucket_off   = (int*)  alloc(NBUCK);
    int*   cursor_p     = (int*)  alloc(NBUCK * 16);
    int2*  ebuf         = (int2*) alloc((size_t)EE * 2);
    float* pool   = (float*)alloc(GG * 128);
    int*   rp     = (int*)  alloc(NN + 1);
    float* dis    = (float*)alloc(NN);
    float* invdis = (float*)alloc(NN);
    float* dsum   = (float*)alloc(NN);
    float* xs     = (float*)alloc(NN);
    int*   col    = (int*)  alloc(EE);
    float* hbuf   = (float*)alloc((size_t)NN * 128);  // hs (16/32/64ch) and raw h4 (128ch)
    float* abuf   = (float*)alloc((size_t)NN * 64);   // aggregated conv inputs (<=64 ch)

    hipMemsetAsync(d_ws, 0, zero_bytes, stream);

    auto nb = [](long long total){ return (int)((total + 255) / 256); };

    // ---- CSR build via LDS-binned radix partition (no global random scatter) ----
    k_hist   <<<NEB, 256, 0, stream>>>(ei + EE, bucket_cnt_p, EE);
    k_bscan  <<<1, 512, 0, stream>>>(bucket_cnt_p, bucket_off, cursor_p);
    k_scatter<<<NEB, 256, 0, stream>>>(ei, ei + EE, cursor_p, ebuf, EE);
    k_build  <<<NBUCK, 256, 0, stream>>>(ebuf, bucket_cnt_p, bucket_off, rp, col, dis, invdis, x, xs, NN);

    // ---- layer 1: fused CSR-walk (agg xs + dsum) + 1->16 linear+gelu (pre-scaled), stats ----
    k_g1l1<<<NB_NODE, 256, 0, stream>>>(xs, dis, rp, col, W1, b1, dsum, hbuf, NN);
    k_stats<16><<<128, 256, 0, stream>>>(hbuf, invdis, stats + 0, NN);

    // ---- layer 2: gather hs1 (BN1 inline), 16->32 linear+gelu (pre-scaled), stats ----
    k_gather<16><<<nb((long long)NN * 4), 256, 0, stream>>>(hbuf, rp, col, dis, dsum, stats + 0, g1, be1, abuf, NN);
    k_linT<16, 32, true><<<nb((long long)(NN / 2) * 8), 256, 0, stream>>>(abuf, dis, W2, b2, hbuf, NN);
    k_stats<32><<<128, 256, 0, stream>>>(hbuf, invdis, stats + 256, NN);

    // ---- layer 3: gather hs2 (BN2 inline), 32->64 linear+gelu (pre-scaled), stats ----
    k_gather<32><<<nb((long long)NN * 8), 256, 0, stream>>>(hbuf, rp, col, dis, dsum, stats + 256, g2, be2, abuf, NN);
    k_linT<32, 64, true><<<nb((long long)(NN / 2) * 16), 256, 0, stream>>>(abuf, dis, W3, b3, hbuf, NN);
    k_stats<64><<<128, 256, 0, stream>>>(hbuf, invdis, stats + 512, NN);

    // ---- layer 4: gather hs3 (BN3 inline), 64->128 linear+gelu (raw out), mean pool ----
    k_gather<64><<<nb((long long)NN * 16), 256, 0, stream>>>(hbuf, rp, col, dis, dsum, stats + 512, g3, be3, abuf, NN);
    k_linT<64, 128, false><<<nb((long long)(NN / 2) * 32), 256, 0, stream>>>(abuf, dis, W4, b4, hbuf, NN);
    k_pool<<<GG, 128, 0, stream>>>(hbuf, batch, pool, NN);

    // ---- MLP head ----
    k_mlp<<<GG, 128, 0, stream>>>(pool, yex,
                                  lw1, lb1, lw2, lb2, lw3, lb3, lw4, lb4, out);
}

// Round 11
// 366.771 us; speedup vs baseline: 1.3431x; 1.0207x over previous
//
#include <hip/hip_runtime.h>
#include <math.h>

#define NN 50000
#define EE 800000
#define GG 256
#define NPB 100          // nodes per bucket
#define NBUCK 500        // NN / NPB exactly
#define EPB 4096         // edges per block chunk (hist/scatter)
#define NEB 196          // ceil(EE/EPB)
#define NB_NODE 196      // ceil(NN/256) node-parallel grids

__device__ __forceinline__ float gelu_f(float v){
    return 0.5f * v * (1.0f + erff(v * 0.70710678118654752f));
}

// ---------------- bucket histogram of dst (LDS-privatized, padded global) ----------------
__global__ __launch_bounds__(256) void k_hist(const int* __restrict__ dst, int* __restrict__ bucket_cnt_p, int e){
    __shared__ int hist[512];
    int t = threadIdx.x;
    int start = blockIdx.x * EPB;
    for (int k = t; k < 512; k += 256) hist[k] = 0;
    __syncthreads();
#pragma unroll
    for (int k = 0; k < EPB / 256; k++){
        int idx = start + k * 256 + t;
        if (idx < e) atomicAdd(&hist[dst[idx] / NPB], 1);
    }
    __syncthreads();
    for (int k = t; k < NBUCK; k += 256){
        int h = hist[k];
        if (h) atomicAdd(&bucket_cnt_p[k * 16], h);   // *16: one cache line per bucket
    }
}

// ---------------- scan bucket counts -> offsets + scatter cursors ----------------
__global__ __launch_bounds__(512) void k_bscan(const int* __restrict__ bucket_cnt_p,
                                               int* __restrict__ bucket_off, int* __restrict__ cursor_p){
    __shared__ int s[512];
    int t = threadIdx.x;
    int v = (t < NBUCK) ? bucket_cnt_p[t * 16] : 0;
    s[t] = v;
    __syncthreads();
    for (int off = 1; off < 512; off <<= 1){
        int u = (t >= off) ? s[t - off] : 0;
        __syncthreads();
        s[t] += u;
        __syncthreads();
    }
    if (t < NBUCK){
        int ex = s[t] - v;
        bucket_off[t] = ex;
        cursor_p[t * 16] = ex;
    }
}

// ---------------- partition (src,dst) pairs into bucket-contiguous ebuf ----------------
__global__ __launch_bounds__(256) void k_scatter(const int* __restrict__ src, const int* __restrict__ dst,
                                                 int* __restrict__ cursor_p, int2* __restrict__ ebuf, int e){
    __shared__ int hist[512], base[512];
    int t = threadIdx.x;
    int start = blockIdx.x * EPB;
    for (int k = t; k < 512; k += 256) hist[k] = 0;
    __syncthreads();
    int ss[EPB / 256], dd[EPB / 256], bb[EPB / 256];
    int cntl = 0;
#pragma unroll
    for (int k = 0; k < EPB / 256; k++){
        int idx = start + k * 256 + t;
        if (idx < e){
            int s_ = src[idx], d_ = dst[idx];
            int b_ = d_ / NPB;
            ss[cntl] = s_; dd[cntl] = d_; bb[cntl] = b_;
            atomicAdd(&hist[b_], 1);
            cntl++;
        }
    }
    __syncthreads();
    for (int k = t; k < NBUCK; k += 256){
        int h = hist[k];
        base[k] = h ? atomicAdd(&cursor_p[k * 16], h) : 0;
    }
    __syncthreads();
    for (int k = t; k < 512; k += 256) hist[k] = 0;
    __syncthreads();
    for (int k = 0; k < cntl; k++){
        int b_ = bb[k];
        int pos = base[b_] + atomicAdd(&hist[b_], 1);
        ebuf[pos] = make_int2(ss[k], dd[k]);
    }
}

// ---------------- per-bucket CSR finalize: node deg/rp/col + dis/invdis/xs (LDS only) ----------------
__global__ __launch_bounds__(256) void k_build(const int2* __restrict__ ebuf,
                                               const int* __restrict__ bucket_cnt_p,
                                               const int* __restrict__ bucket_off,
                                               int* __restrict__ rp, int* __restrict__ col,
                                               float* __restrict__ dis, float* __restrict__ invdis,
                                               const float* __restrict__ x, float* __restrict__ xs, int n){
    int b = blockIdx.x;
    int t = threadIdx.x;
    int nbase = b * NPB;
    int eoff = bucket_off[b];
    int ecnt = bucket_cnt_p[b * 16];
    __shared__ int cnt[128], excl[128], cnt2[128], s[128];
    if (t < 128){ cnt[t] = 0; cnt2[t] = 0; }
    __syncthreads();
    for (int j = t; j < ecnt; j += 256)
        atomicAdd(&cnt[ebuf[eoff + j].y - nbase], 1);
    __syncthreads();
    int v = (t < 128) ? cnt[t] : 0;
    if (t < 128) s[t] = v;
    __syncthreads();
    for (int off = 1; off < 128; off <<= 1){
        int u = (t < 128 && t >= off) ? s[t - off] : 0;
        __syncthreads();
        if (t < 128) s[t] += u;
        __syncthreads();
    }
    if (t < 128) excl[t] = s[t] - v;
    __syncthreads();
    if (t < NPB){
        int node = nbase + t;      // NBUCK*NPB == NN exactly
        int dgg = cnt[t];
        rp[node] = eoff + excl[t];
        float dv = rsqrtf((float)(dgg + 1));   // +1 self loop
        dis[node] = dv;
        invdis[node] = sqrtf((float)(dgg + 1));
        xs[node] = dv * x[node];
    }
    if (b == NBUCK - 1 && t == 0) rp[n] = eoff + ecnt;   // == E
    __syncthreads();
    for (int j = t; j < ecnt; j += 256){
        int2 e2 = ebuf[eoff + j];
        int li = e2.y - nbase;
        int p = eoff + excl[li] + atomicAdd(&cnt2[li], 1);
        col[p] = e2.x;             // 6.4KB window per bucket -> full line reuse
    }
}

// ---------------- fused: CSR walk (agg xs, dsum) + layer-1 1->16 linear+GELU+prescale ----------------
__global__ __launch_bounds__(256) void k_g1l1(const float* __restrict__ xs, const float* __restrict__ dis,
                                              const int* __restrict__ rp, const int* __restrict__ col,
                                              const float* __restrict__ W, const float* __restrict__ bias,
                                              float* __restrict__ dsum, float* __restrict__ hs, int n){
    int node = blockIdx.x * 256 + threadIdx.x;
    if (node >= n) return;
    int beg = rp[node], end = rp[node + 1];
    float a0 = 0.f, a1 = 0.f, d0 = 0.f, d1 = 0.f;
    int j = beg;
    for (; j + 1 < end; j += 2){
        int c0 = col[j], c1 = col[j + 1];
        a0 += xs[c0]; d0 += dis[c0];
        a1 += xs[c1]; d1 += dis[c1];
    }
    if (j < end){ int c = col[j]; a0 += xs[c]; d0 += dis[c]; }
    float dn = dis[node];
    dsum[node] = d0 + d1 + dn;
    float a = dn * (a0 + a1 + xs[node]);
    float4* o = (float4*)(hs + (size_t)node * 16);
#pragma unroll
    for (int u = 0; u < 4; u++){
        float4 r;
        r.x = gelu_f(bias[u*4+0] + a * W[u*4+0]) * dn;
        r.y = gelu_f(bias[u*4+1] + a * W[u*4+1]) * dn;
        r.z = gelu_f(bias[u*4+2] + a * W[u*4+2]) * dn;
        r.w = gelu_f(bias[u*4+3] + a * W[u*4+3]) * dn;
        o[u] = r;
    }
}

// ---------------- gather of pre-scaled hs with inline BN affine (float4, 8-edge unroll) ----------------
// out[d] = dis_d * ( sc * (sum_{s in N(d)} hs[s] + hs[d]) + sh * dsum[d] )
template<int C>
__global__ __launch_bounds__(256) void k_gather(const float* __restrict__ hs, const int* __restrict__ rp,
                                                const int* __restrict__ col, const float* __restrict__ dis,
                                                const float* __restrict__ dsum, const float* __restrict__ stat,
                                                const float* __restrict__ gamma, const float* __restrict__ beta,
                                                float* __restrict__ outp, int n){
    constexpr int TPN = C / 4;
    int i = blockIdx.x * 256 + threadIdx.x;
    int node = i / TPN, q = i % TPN;
    if (node >= n) return;
    int c0 = q * 4;
    const float invn = 1.0f / (float)NN;
    float scv[4], shv[4];
#pragma unroll
    for (int u = 0; u < 4; u++){
        float mean = stat[c0 + u] * invn;
        float var  = stat[128 + c0 + u] * invn - mean * mean;
        float sc   = gamma[c0 + u] * rsqrtf(var + 1e-5f);
        scv[u] = sc;
        shv[u] = beta[c0 + u] - mean * sc;
    }
    const float4* h4 = (const float4*)hs;
    int beg = rp[node], end = rp[node + 1];
    float a0 = 0.f, a1 = 0.f, a2 = 0.f, a3 = 0.f;
    float b0 = 0.f, b1 = 0.f, b2 = 0.f, b3 = 0.f;
    int j = beg;
    // 8-edge unroll: 8 outstanding float4 gathers per thread (latency-bound loop)
    for (; j + 7 < end; j += 8){
        int i0 = col[j],   i1 = col[j+1], i2 = col[j+2], i3 = col[j+3];
        int i4 = col[j+4], i5 = col[j+5], i6 = col[j+6], i7 = col[j+7];
        float4 v0 = h4[i0 * TPN + q];
        float4 v1 = h4[i1 * TPN + q];
        float4 v2 = h4[i2 * TPN + q];
        float4 v3 = h4[i3 * TPN + q];
        float4 v4 = h4[i4 * TPN + q];
        float4 v5 = h4[i5 * TPN + q];
        float4 v6 = h4[i6 * TPN + q];
        float4 v7 = h4[i7 * TPN + q];
        a0 += v0.x; a1 += v0.y; a2 += v0.z; a3 += v0.w;
        b0 += v1.x; b1 += v1.y; b2 += v1.z; b3 += v1.w;
        a0 += v2.x; a1 += v2.y; a2 += v2.z; a3 += v2.w;
        b0 += v3.x; b1 += v3.y; b2 += v3.z; b3 += v3.w;
        a0 += v4.x; a1 += v4.y; a2 += v4.z; a3 += v4.w;
        b0 += v5.x; b1 += v5.y; b2 += v5.z; b3 += v5.w;
        a0 += v6.x; a1 += v6.y; a2 += v6.z; a3 += v6.w;
        b0 += v7.x; b1 += v7.y; b2 += v7.z; b3 += v7.w;
    }
    for (; j < end; j++){
        float4 v = h4[col[j] * TPN + q];
        a0 += v.x; a1 += v.y; a2 += v.z; a3 += v.w;
    }
    float4 vs = h4[node * TPN + q];    // self loop (weight 1 in pre-scaled space)
    a0 += vs.x; a1 += vs.y; a2 += vs.z; a3 += vs.w;
    a0 += b0; a1 += b1; a2 += b2; a3 += b3;
    float dn = dis[node];
    float dsm = dsum[node];
    float4 r = make_float4((a0 * scv[0] + shv[0] * dsm) * dn,
                           (a1 * scv[1] + shv[1] * dsm) * dn,
                           (a2 * scv[2] + shv[2] * dsm) * dn,
                           (a3 * scv[3] + shv[3] * dsm) * dn);
    ((float4*)outp)[node * TPN + q] = r;
}

// ---------------- dense linear + bias + GELU: 4 nodes x 4 channels per thread ----------------
// unroll 1 K-loop: 8 independent float4 loads feed 64 FMAs per iter (load:FMA 1:8).
// Live set ~48 floats -> ~70 VGPR (mid-range; avoids both the 256-spill and 32-squeeze cliffs).
template<int CIN, int COUT, bool SCALE>
__global__ __launch_bounds__(256) void k_linT(const float* __restrict__ xin, const float* __restrict__ dis,
                                              const float* __restrict__ W,
                                              const float* __restrict__ bias, float* __restrict__ outp, int n){
    constexpr int QC = COUT / 4;
    constexpr int K4 = CIN / 4;
    int i = blockIdx.x * 256 + threadIdx.x;
    int tile = i / QC, q = i % QC;
    int n0 = tile * 4;                 // NN % 4 == 0
    if (n0 >= n) return;
    const float4* xp0 = (const float4*)(xin + (size_t)(n0 + 0) * CIN);
    const float4* xp1 = (const float4*)(xin + (size_t)(n0 + 1) * CIN);
    const float4* xp2 = (const float4*)(xin + (size_t)(n0 + 2) * CIN);
    const float4* xp3 = (const float4*)(xin + (size_t)(n0 + 3) * CIN);
    const float4* Wq = (const float4*)W + q;      // row k at Wq[k * QC]
    float4 bb = ((const float4*)bias)[q];
    float acc[4][4];
#pragma unroll
    for (int nd = 0; nd < 4; nd++){
        acc[nd][0] = bb.x; acc[nd][1] = bb.y; acc[nd][2] = bb.z; acc[nd][3] = bb.w;
    }
#pragma unroll 1
    for (int k4 = 0; k4 < K4; k4++){
        float4 xv[4];
        xv[0] = xp0[k4]; xv[1] = xp1[k4]; xv[2] = xp2[k4]; xv[3] = xp3[k4];
        float4 w0 = Wq[(k4 * 4 + 0) * QC];
        float4 w1 = Wq[(k4 * 4 + 1) * QC];
        float4 w2 = Wq[(k4 * 4 + 2) * QC];
        float4 w3 = Wq[(k4 * 4 + 3) * QC];
#pragma unroll
        for (int nd = 0; nd < 4; nd++){
            acc[nd][0] += xv[nd].x*w0.x + xv[nd].y*w1.x + xv[nd].z*w2.x + xv[nd].w*w3.x;
            acc[nd][1] += xv[nd].x*w0.y + xv[nd].y*w1.y + xv[nd].z*w2.y + xv[nd].w*w3.y;
            acc[nd][2] += xv[nd].x*w0.z + xv[nd].y*w1.z + xv[nd].z*w2.z + xv[nd].w*w3.z;
            acc[nd][3] += xv[nd].x*w0.w + xv[nd].y*w1.w + xv[nd].z*w2.w + xv[nd].w*w3.w;
        }
    }
    float4* o4 = (float4*)outp;
#pragma unroll
    for (int nd = 0; nd < 4; nd++){
        float sc = SCALE ? dis[n0 + nd] : 1.0f;
        o4[(size_t)(n0 + nd) * QC + q] =
            make_float4(gelu_f(acc[nd][0])*sc, gelu_f(acc[nd][1])*sc,
                        gelu_f(acc[nd][2])*sc, gelu_f(acc[nd][3])*sc);
    }
}

// ---------------- BN stats over raw h (de-scale pre-scaled hs by invdis) ----------------
template<int C>
__global__ __launch_bounds__(256) void k_stats(const float* __restrict__ hs, const float* __restrict__ invdis,
                                               float* __restrict__ stat, int n){
    constexpr int REP = 256 / C;
    int t = threadIdx.x;
    int rep = t / C;
    int c = t % C;
    float s = 0.f, q = 0.f;
    for (int row = blockIdx.x * REP + rep; row < n; row += gridDim.x * REP){
        float v = hs[(long long)row * C + c] * invdis[row];
        s += v; q += v * v;
    }
    __shared__ float ss[256], sq[256];
    ss[t] = s; sq[t] = q;
    __syncthreads();
    for (int off = 128; off >= C; off >>= 1){
        if (t < off){ ss[t] += ss[t + off]; sq[t] += sq[t + off]; }
        __syncthreads();
    }
    if (t < C){
        atomicAdd(&stat[t], ss[t]);
        atomicAdd(&stat[128 + t], sq[t]);
    }
}

// ---------------- mean-pool: one block per graph, binary search sorted batch, no atomics ----------------
__global__ __launch_bounds__(128) void k_pool(const float* __restrict__ h4, const int* __restrict__ batch,
                                              float* __restrict__ pool, int n){
    int g = blockIdx.x;
    int t = threadIdx.x;
    int lo = 0, hi = n;
    while (lo < hi){ int mid = (lo + hi) >> 1; if (batch[mid] < g) lo = mid + 1; else hi = mid; }
    int s = lo;
    hi = n;
    while (lo < hi){ int mid = (lo + hi) >> 1; if (batch[mid] < g + 1) lo = mid + 1; else hi = mid; }
    int e = lo;
    float a0 = 0.f, a1 = 0.f, a2 = 0.f, a3 = 0.f;
    int node = s;
    for (; node + 3 < e; node += 4){
        a0 += h4[(size_t)(node + 0) * 128 + t];
        a1 += h4[(size_t)(node + 1) * 128 + t];
        a2 += h4[(size_t)(node + 2) * 128 + t];
        a3 += h4[(size_t)(node + 3) * 128 + t];
    }
    for (; node < e; node++) a0 += h4[(size_t)node * 128 + t];
    float sum = (a0 + a1) + (a2 + a3);
    pool[g * 128 + t] = sum / fmaxf((float)(e - s), 1.0f);
}

// ---------------- MLP head: 256 graphs, one block each ----------------
__global__ __launch_bounds__(128) void k_mlp(const float* __restrict__ pool,
                                             const float* __restrict__ yex,
                                             const float* __restrict__ lw1, const float* __restrict__ lb1,
                                             const float* __restrict__ lw2, const float* __restrict__ lb2,
                                             const float* __restrict__ lw3, const float* __restrict__ lb3,
                                             const float* __restrict__ lw4, const float* __restrict__ lb4,
                                             float* __restrict__ outp){
    int g = blockIdx.x;
    int t = threadIdx.x;
    __shared__ float z[136];
    __shared__ float z2[128];
    __shared__ float z3[64];
    __shared__ float z4[32];
    z[t] = pool[g * 128 + t];
    if (t < 7) z[128 + t] = yex[g * 7 + t];
    __syncthreads();
    {   // 135 -> 128
        float acc = lb1[t];
        for (int k = 0; k < 135; k++) acc += z[k] * lw1[k * 128 + t];
        z2[t] = gelu_f(acc);
    }
    __syncthreads();
    if (t < 64){   // 128 -> 64
        float acc = lb2[t];
        for (int k = 0; k < 128; k++) acc += z2[k] * lw2[k * 64 + t];
        z3[t] = gelu_f(acc);
    }
    __syncthreads();
    if (t < 32){   // 64 -> 32
        float acc = lb3[t];
        for (int k = 0; k < 64; k++) acc += z3[k] * lw3[k * 32 + t];
        z4[t] = gelu_f(acc);
    }
    __syncthreads();
    if (t < 2){    // 32 -> 2, sigmoid
        float acc = lb4[t];
        for (int k = 0; k < 32; k++) acc += z4[k] * lw4[k * 2 + t];
        outp[g * 2 + t] = 1.0f / (1.0f + expf(-acc));
    }
}

extern "C" void kernel_launch(void* const* d_in, const int* in_sizes, int n_in,
                              void* d_out, int out_size, void* d_ws, size_t ws_size,
                              hipStream_t stream) {
    const float* x     = (const float*)d_in[0];
    const int*   ei    = (const int*)  d_in[1];   // [2, E]: src = ei, dst = ei+E
    const int*   batch = (const int*)  d_in[2];
    const float* yex   = (const float*)d_in[3];
    const float* W1 = (const float*)d_in[4];  const float* b1 = (const float*)d_in[5];
    const float* W2 = (const float*)d_in[6];  const float* b2 = (const float*)d_in[7];
    const float* W3 = (const float*)d_in[8];  const float* b3 = (const float*)d_in[9];
    const float* W4 = (const float*)d_in[10]; const float* b4 = (const float*)d_in[11];
    const float* g1 = (const float*)d_in[12]; const float* be1 = (const float*)d_in[13];
    const float* g2 = (const float*)d_in[14]; const float* be2 = (const float*)d_in[15];
    const float* g3 = (const float*)d_in[16]; const float* be3 = (const float*)d_in[17];
    const float* lw1 = (const float*)d_in[18]; const float* lb1 = (const float*)d_in[19];
    const float* lw2 = (const float*)d_in[20]; const float* lb2 = (const float*)d_in[21];
    const float* lw3 = (const float*)d_in[22]; const float* lb3 = (const float*)d_in[23];
    const float* lw4 = (const float*)d_in[24]; const float* lb4 = (const float*)d_in[25];
    float* out = (float*)d_out;

    // ---- workspace carve (256B-aligned); zero-region first ----
    char* wsb = (char*)d_ws;
    size_t off = 0;
    auto alloc = [&](size_t elems) -> void* {
        void* p = wsb + off;
        off += ((elems * 4 + 255) / 256) * 256;
        return p;
    };
    float* stats        = (float*)alloc(3 * 256);      // layer l: [l*256+c]=sum, [+128]=sumsq
    int*   bucket_cnt_p = (int*)  alloc(NBUCK * 16);   // padded: 1 line per bucket
    size_t zero_bytes = off;
    int*   bucket_off   = (int*)  alloc(NBUCK);
    int*   cursor_p     = (int*)  alloc(NBUCK * 16);
    int2*  ebuf         = (int2*) alloc((size_t)EE * 2);
    float* pool   = (float*)alloc(GG * 128);
    int*   rp     = (int*)  alloc(NN + 1);
    float* dis    = (float*)alloc(NN);
    float* invdis = (float*)alloc(NN);
    float* dsum   = (float*)alloc(NN);
    float* xs     = (float*)alloc(NN);
    int*   col    = (int*)  alloc(EE);
    float* hbuf   = (float*)alloc((size_t)NN * 128);  // hs (16/32/64ch) and raw h4 (128ch)
    float* abuf   = (float*)alloc((size_t)NN * 64);   // aggregated conv inputs (<=64 ch)

    hipMemsetAsync(d_ws, 0, zero_bytes, stream);

    auto nb = [](long long total){ return (int)((total + 255) / 256); };

    // ---- CSR build via LDS-binned radix partition (no global random scatter) ----
    k_hist   <<<NEB, 256, 0, stream>>>(ei + EE, bucket_cnt_p, EE);
    k_bscan  <<<1, 512, 0, stream>>>(bucket_cnt_p, bucket_off, cursor_p);
    k_scatter<<<NEB, 256, 0, stream>>>(ei, ei + EE, cursor_p, ebuf, EE);
    k_build  <<<NBUCK, 256, 0, stream>>>(ebuf, bucket_cnt_p, bucket_off, rp, col, dis, invdis, x, xs, NN);

    // ---- layer 1: fused CSR-walk (agg xs + dsum) + 1->16 linear+gelu (pre-scaled), stats ----
    k_g1l1<<<NB_NODE, 256, 0, stream>>>(xs, dis, rp, col, W1, b1, dsum, hbuf, NN);
    k_stats<16><<<128, 256, 0, stream>>>(hbuf, invdis, stats + 0, NN);

    // ---- layer 2: gather hs1 (BN1 inline), 16->32 linear+gelu (pre-scaled), stats ----
    k_gather<16><<<nb((long long)NN * 4), 256, 0, stream>>>(hbuf, rp, col, dis, dsum, stats + 0, g1, be1, abuf, NN);
    k_linT<16, 32, true><<<nb((long long)(NN / 4) * 8), 256, 0, stream>>>(abuf, dis, W2, b2, hbuf, NN);
    k_stats<32><<<128, 256, 0, stream>>>(hbuf, invdis, stats + 256, NN);

    // ---- layer 3: gather hs2 (BN2 inline), 32->64 linear+gelu (pre-scaled), stats ----
    k_gather<32><<<nb((long long)NN * 8), 256, 0, stream>>>(hbuf, rp, col, dis, dsum, stats + 256, g2, be2, abuf, NN);
    k_linT<32, 64, true><<<nb((long long)(NN / 4) * 16), 256, 0, stream>>>(abuf, dis, W3, b3, hbuf, NN);
    k_stats<64><<<128, 256, 0, stream>>>(hbuf, invdis, stats + 512, NN);

    // ---- layer 4: gather hs3 (BN3 inline), 64->128 linear+gelu (raw out), mean pool ----
    k_gather<64><<<nb((long long)NN * 16), 256, 0, stream>>>(hbuf, rp, col, dis, dsum, stats + 512, g3, be3, abuf, NN);
    k_linT<64, 128, false><<<nb((long long)(NN / 4) * 32), 256, 0, stream>>>(abuf, dis, W4, b4, hbuf, NN);
    k_pool<<<GG, 128, 0, stream>>>(hbuf, batch, pool, NN);

    // ---- MLP head ----
    k_mlp<<<GG, 128, 0, stream>>>(pool, yex,
                                  lw1, lb1, lw2, lb2, lw3, lb3, lw4, lb4, out);
}